// Round 6
// baseline (467.022 us; speedup 1.0000x reference)
//
#include <hip/hip_runtime.h>
#include <hip/hip_bf16.h>
#include <math.h>

// B=4096, S=200, D=64, H=36
#define BB 4096
#define SS 200
#define DD 64
#define HH 36
#define NP 48            // H padded to 3 n-tiles of 16
#define LDH 72           // LDS row stride (bf16): 144 B rows -> 16B-aligned b128
#define NROWSF (4096.0f * 200.0f)
#define NPB (2 * BB)     // 8192 blocks: (b, half)
#define PSTRIDE 80       // per-block partial-stat row stride (dwords)
#define HSLOT 768        // bf16 per (block, tile) h-fragment slot = 16x48

typedef short bf16x8 __attribute__((ext_vector_type(8)));
typedef float f32x4 __attribute__((ext_vector_type(4)));

__device__ __forceinline__ unsigned short f2bf(float f) {
    union { float f; unsigned u; } v; v.f = f;
    unsigned r = v.u + 0x7FFFu + ((v.u >> 16) & 1u);   // RNE
    return (unsigned short)(r >> 16);
}
__device__ __forceinline__ unsigned f2bf2(float a, float b) {
    union { __hip_bfloat162 h; unsigned u; } v;
    v.h = __float22bfloat162_rn(float2{a, b});         // a->low, b->high
    return v.u;
}
__device__ __forceinline__ float bf2f(unsigned short h) {
    union { unsigned u; float f; } v; v.u = (unsigned)h << 16;
    return v.f;
}
__device__ __forceinline__ float2 bf2x2(unsigned u) {
    union { unsigned q; float f; } a, b;
    a.q = u << 16; b.q = u & 0xFFFF0000u;
    return float2{a.f, b.f};
}

// ---------------------------------------------------------------------------
// k_wb: per-b folded weights/bias, computed once.
//   Wb[k][n] = W1b[k][n] - W1c[k][n] + c[k]*W1d[k][n]
//   base[n]  = b1[n] + sum_k c[k]*(W1a[k][n] + W1c[k][n])
// ---------------------------------------------------------------------------
__global__ __launch_bounds__(256) void k_wb(const float* __restrict__ cand,
                                            const float* __restrict__ W1,
                                            const float* __restrict__ b1,
                                            unsigned short* __restrict__ WbG,
                                            float* __restrict__ baseG) {
    int b = blockIdx.x, t = threadIdx.x;
    __shared__ float shC[DD];
    if (t < DD) shC[t] = cand[b * DD + t];
    __syncthreads();
    unsigned short* wb = WbG + (size_t)b * (NP * DD);
#pragma unroll
    for (int u = 0; u < 12; ++u) {              // 48*64/256
        int e = t + u * 256;
        int n = e >> 6, k = e & 63;
        float val = 0.f;
        if (n < HH)
            val = W1[(DD + k) * HH + n] - W1[(2 * DD + k) * HH + n] +
                  shC[k] * W1[(3 * DD + k) * HH + n];
        wb[e] = f2bf(val);
    }
    if (t < NP) {
        float v = 0.f;
        if (t < HH) {
            v = b1[t];
            for (int k = 0; k < DD; ++k)
                v += shC[k] * (W1[k * HH + t] + W1[(2 * DD + k) * HH + t]);
        }
        baseG[b * NP + t] = v;
    }
}

// ---------------------------------------------------------------------------
// Prologue: stage half of hist (fp32 -> bf16 LDS, packed cvt) + WbT/base.
// WB=true: vector-load precomputed WbG/baseG (1 barrier). WB=false: in-block.
// ---------------------------------------------------------------------------
template <bool WB>
__device__ __forceinline__ void prologue(int b, int half, int t,
                                         const float* __restrict__ hist,
                                         const float* __restrict__ cand,
                                         const float* __restrict__ W1,
                                         const float* __restrict__ b1,
                                         const unsigned short* __restrict__ WbG,
                                         const float* __restrict__ baseG,
                                         unsigned short* shH, unsigned short* shWbT,
                                         float* shC, float* shBase,
                                         float (*shBaseP)[NP]) {
    const float4* src =
        (const float4*)(hist + ((size_t)b * SS + (half ? 112 : 0)) * DD);
    float4 v[7];
    uint4 w0 = {}, w1 = {};
    float bse = 0.f;
    if (WB) {
        const uint4* wsrc = (const uint4*)(WbG + (size_t)b * (NP * DD));
        w0 = wsrc[t];
        if (t < 128) w1 = wsrc[256 + t];
        if (t < NP) bse = baseG[b * NP + t];
    } else {
        if (t < DD) shC[t] = cand[b * DD + t];
    }
    if (!half) {
#pragma unroll
        for (int u = 0; u < 7; ++u) v[u] = src[t + u * 256];
    } else {
#pragma unroll
        for (int u = 0; u < 5; ++u) v[u] = src[t + u * 256];
        if (t < 128) v[5] = src[t + 1280];
        *(unsigned*)&shH[(88 + (t >> 5)) * LDH + (t & 31) * 2] = 0;  // pad rows
    }
    if (!WB) __syncthreads();
#pragma unroll
    for (int u = 0; u < 7; ++u) {
        int i = t + u * 256;
        bool act = half ? (u < 5 || (u == 5 && t < 128)) : true;
        if (u < 6 || !half) {
            if (act) {
                int s = i >> 4, c = i & 15;
                uint2 o = {f2bf2(v[u].x, v[u].y), f2bf2(v[u].z, v[u].w)};
                *(uint2*)&shH[s * LDH + c * 4] = o;
            }
        }
    }
    if (WB) {
        *(uint4*)&shWbT[(t >> 3) * LDH + (t & 7) * 8] = w0;
        if (t < 128) *(uint4*)&shWbT[(32 + (t >> 3)) * LDH + (t & 7) * 8] = w1;
        if (t < NP) shBase[t] = bse;
        __syncthreads();
    } else {
        for (int e = t; e < NP * DD; e += 256) {
            int n = e >> 6, k = e & 63;
            float val = 0.f;
            if (n < HH)
                val = W1[(DD + k) * HH + n] - W1[(2 * DD + k) * HH + n] +
                      shC[k] * W1[(3 * DD + k) * HH + n];
            shWbT[n * LDH + k] = f2bf(val);
        }
        if (t < 4 * NP) {
            int g = t / NP, j = t - g * NP;
            float p = 0.f;
            if (j < HH) {
#pragma unroll 4
                for (int k = 16 * g; k < 16 * g + 16; ++k)
                    p += shC[k] * (W1[k * HH + j] + W1[(2 * DD + k) * HH + j]);
            }
            shBaseP[g][j] = p;
        }
        __syncthreads();
        if (t < NP) {
            float val = (t < HH) ? b1[t] : 0.f;
            shBase[t] = val + shBaseP[0][t] + shBaseP[1][t] + shBaseP[2][t] +
                        shBaseP[3][t];
        }
        __syncthreads();
    }
}

__device__ __forceinline__ void load_bfrags(const unsigned short* shWbT, int lane,
                                            bf16x8 (&bfr)[3][2]) {
    int col = lane & 15, q = lane >> 4;
#pragma unroll
    for (int nt = 0; nt < 3; ++nt)
#pragma unroll
        for (int kt = 0; kt < 2; ++kt)
            bfr[nt][kt] = *(const bf16x8*)&shWbT[(nt * 16 + col) * LDH + kt * 32 + q * 8];
}

__device__ __forceinline__ void gemm_tile(const unsigned short* shH,
                                          const bf16x8 (&bfr)[3][2], int mt, int lane,
                                          f32x4 (&d)[3]) {
    int m = mt * 16 + (lane & 15), q = lane >> 4;
    d[0] = f32x4{0.f, 0.f, 0.f, 0.f};
    d[1] = f32x4{0.f, 0.f, 0.f, 0.f};
    d[2] = f32x4{0.f, 0.f, 0.f, 0.f};
#pragma unroll
    for (int kt = 0; kt < 2; ++kt) {
        bf16x8 a = *(const bf16x8*)&shH[m * LDH + kt * 32 + q * 8];
#pragma unroll
        for (int nt = 0; nt < 3; ++nt)
            d[nt] = __builtin_amdgcn_mfma_f32_16x16x32_bf16(a, bfr[nt][kt], d[nt], 0, 0, 0);
    }
}

// ---------------------------------------------------------------------------
// Pass 1: BN column stats; HS=true additionally stores h (d+base) as bf16
// fragments to hG — 6 coalesced dword stores/thread/tile, no transpose.
// ---------------------------------------------------------------------------
template <bool WB, bool RED, bool HS>
__global__ __launch_bounds__(256, 6) void k_pass1(const float* __restrict__ hist,
                                                  const float* __restrict__ cand,
                                                  const float* __restrict__ W1,
                                                  const float* __restrict__ b1,
                                                  const unsigned short* __restrict__ WbG,
                                                  const float* __restrict__ baseG,
                                                  unsigned short* __restrict__ hG,
                                                  float* __restrict__ pstat,
                                                  float* __restrict__ gsum,
                                                  float* __restrict__ gsum2) {
    __shared__ unsigned short shH[112 * LDH];
    __shared__ unsigned short shWbT[NP * LDH];
    __shared__ float shC[WB ? 1 : DD], shBase[NP];
    __shared__ float shBaseP[WB ? 1 : 4][NP];
    __shared__ float shP1[4][NP], shP2[4][NP];
    int bx = blockIdx.x, b = bx >> 1, half = bx & 1;
    int t = threadIdx.x, wave = t >> 6, lane = t & 63;
    int col = lane & 15, q = lane >> 4;

    prologue<WB>(b, half, t, hist, cand, W1, b1, WbG, baseG, shH, shWbT, shC,
                 shBase, shBaseP);

    bf16x8 bfr[3][2];
    load_bfrags(shWbT, lane, bfr);
    float basev[3];
#pragma unroll
    for (int nt = 0; nt < 3; ++nt) basev[nt] = shBase[nt * 16 + col];

    const int NTl = half ? 6 : 7;
    float cs1[3] = {0.f, 0.f, 0.f}, cs2[3] = {0.f, 0.f, 0.f};
    for (int mt = wave; mt < NTl; mt += 4) {
        f32x4 d[3];
        gemm_tile(shH, bfr, mt, lane, d);
        float vv[3][4];
#pragma unroll
        for (int nt = 0; nt < 3; ++nt)
#pragma unroll
            for (int r = 0; r < 4; ++r) vv[nt][r] = d[nt][r] + basev[nt];
        if (HS) {
            unsigned* hp = (unsigned*)(hG + ((size_t)bx * 7 + mt) * HSLOT);
#pragma unroll
            for (int nt = 0; nt < 3; ++nt) {
                hp[(nt * 2 + 0) * 64 + lane] = f2bf2(vv[nt][0], vv[nt][1]);
                hp[(nt * 2 + 1) * 64 + lane] = f2bf2(vv[nt][2], vv[nt][3]);
            }
        }
        if (half && mt == 5) {               // ragged tile: exclude pad rows
            int grow0 = 192 + q * 4;
#pragma unroll
            for (int nt = 0; nt < 3; ++nt)
#pragma unroll
                for (int r = 0; r < 4; ++r)
                    if (grow0 + r < SS) {
                        cs1[nt] += vv[nt][r];
                        cs2[nt] += vv[nt][r] * vv[nt][r];
                    }
        } else {
#pragma unroll
            for (int nt = 0; nt < 3; ++nt)
#pragma unroll
                for (int r = 0; r < 4; ++r) {
                    cs1[nt] += vv[nt][r];
                    cs2[nt] += vv[nt][r] * vv[nt][r];
                }
        }
    }
#pragma unroll
    for (int nt = 0; nt < 3; ++nt) {
        cs1[nt] += __shfl_xor(cs1[nt], 16);
        cs1[nt] += __shfl_xor(cs1[nt], 32);
        cs2[nt] += __shfl_xor(cs2[nt], 16);
        cs2[nt] += __shfl_xor(cs2[nt], 32);
    }
    if (lane < 16) {
#pragma unroll
        for (int nt = 0; nt < 3; ++nt) {
            shP1[wave][nt * 16 + lane] = cs1[nt];
            shP2[wave][nt * 16 + lane] = cs2[nt];
        }
    }
    __syncthreads();
    if (RED) {
        if (t < HH)
            pstat[(size_t)bx * PSTRIDE + t] =
                shP1[0][t] + shP1[1][t] + shP1[2][t] + shP1[3][t];
        else if (t < 2 * HH) {
            int f = t - HH;
            pstat[(size_t)bx * PSTRIDE + t] =
                shP2[0][f] + shP2[1][f] + shP2[2][f] + shP2[3][f];
        }
    } else {
        if (t < HH) {
            atomicAdd(gsum + t, shP1[0][t] + shP1[1][t] + shP1[2][t] + shP1[3][t]);
            atomicAdd(gsum2 + t, shP2[0][t] + shP2[1][t] + shP2[2][t] + shP2[3][t]);
        }
    }
}

// ---------------------------------------------------------------------------
// Stats reduce (RED): block f reduces feature-f partials over 8192 blocks.
// ---------------------------------------------------------------------------
__global__ __launch_bounds__(256) void k_stats_red(const float* __restrict__ pstat,
                                                   const float* __restrict__ gamma,
                                                   const float* __restrict__ beta,
                                                   float* __restrict__ A,
                                                   float* __restrict__ Bc) {
    int f = blockIdx.x, t = threadIdx.x;
    if (f >= HH) {
        if (t == 0) { A[f] = 0.f; Bc[f] = 0.f; }
        return;
    }
    float s1 = 0.f, s2 = 0.f;
    for (int r = t; r < NPB; r += 256) {
        s1 += pstat[(size_t)r * PSTRIDE + f];
        s2 += pstat[(size_t)r * PSTRIDE + HH + f];
    }
#pragma unroll
    for (int off = 1; off < 64; off <<= 1) {
        s1 += __shfl_xor(s1, off);
        s2 += __shfl_xor(s2, off);
    }
    __shared__ float a1[4], a2[4];
    if ((t & 63) == 0) { a1[t >> 6] = s1; a2[t >> 6] = s2; }
    __syncthreads();
    if (t == 0) {
        s1 = a1[0] + a1[1] + a1[2] + a1[3];
        s2 = a2[0] + a2[1] + a2[2] + a2[3];
        float mu = s1 * (1.0f / NROWSF);
        float var = s2 * (1.0f / NROWSF) - mu * mu;
        float a = rsqrtf(var + 1e-5f) * gamma[f];
        A[f] = a;
        Bc[f] = beta[f] - mu * a;
    }
}

__global__ void k_stats(const float* __restrict__ gsum, const float* __restrict__ gsum2,
                        const float* __restrict__ gamma, const float* __restrict__ beta,
                        float* __restrict__ A, float* __restrict__ Bc) {
    int t = threadIdx.x;
    if (t < NP) {
        if (t < HH) {
            float mu = gsum[t] * (1.0f / NROWSF);
            float var = gsum2[t] * (1.0f / NROWSF) - mu * mu;
            float a = rsqrtf(var + 1e-5f) * gamma[t];
            A[t] = a;
            Bc[t] = beta[t] - mu * a;
        } else {
            A[t] = 0.f;
            Bc[t] = 0.f;
        }
    }
}

// ---------------------------------------------------------------------------
// Pass 3 (new fast epilogue): read stored h fragments (coalesced), BN affine,
// Dice, output linear, pool from global hist. No staging, no GEMM, tiny LDS.
// ---------------------------------------------------------------------------
__global__ __launch_bounds__(256, 8) void k_pass3(const unsigned short* __restrict__ hG,
                                                  const float* __restrict__ hist,
                                                  const float* __restrict__ Acoef,
                                                  const float* __restrict__ Bcoef,
                                                  const float* __restrict__ alpha,
                                                  const float* __restrict__ W2,
                                                  const float* __restrict__ b2,
                                                  float* __restrict__ out) {
    __shared__ float shW[112];
    __shared__ float shPool[4][DD];
    int bx = blockIdx.x, b = bx >> 1, half = bx & 1;
    int t = threadIdx.x, wave = t >> 6, lane = t & 63;
    int col = lane & 15, q = lane >> 4;

    float Ar[3], Br[3], W2r[3];
#pragma unroll
    for (int nt = 0; nt < 3; ++nt) {
        int c = nt * 16 + col;
        Ar[nt] = Acoef[c];
        Br[nt] = Bcoef[c];
        W2r[nt] = (c < HH) ? W2[c] : 0.f;
    }
    float alv = alpha[0], one_m_alv = 1.0f - alv, b2v = b2[0];

    const int NTl = half ? 6 : 7;
    for (int mt = wave; mt < NTl; mt += 4) {
        const unsigned* hp = (const unsigned*)(hG + ((size_t)bx * 7 + mt) * HSLOT);
        float h[3][4];
#pragma unroll
        for (int nt = 0; nt < 3; ++nt) {
            float2 lo = bf2x2(hp[(nt * 2 + 0) * 64 + lane]);
            float2 hi = bf2x2(hp[(nt * 2 + 1) * 64 + lane]);
            h[nt][0] = fmaf(lo.x, Ar[nt], Br[nt]);
            h[nt][1] = fmaf(lo.y, Ar[nt], Br[nt]);
            h[nt][2] = fmaf(hi.x, Ar[nt], Br[nt]);
            h[nt][3] = fmaf(hi.y, Ar[nt], Br[nt]);
        }
        float s1[4], s2[4], wsum[4];
#pragma unroll
        for (int r = 0; r < 4; ++r) {
            s1[r] = h[0][r] + h[1][r] + h[2][r];
            s2[r] = h[0][r] * h[0][r] + h[1][r] * h[1][r] + h[2][r] * h[2][r];
            s1[r] += __shfl_xor(s1[r], 1);
            s1[r] += __shfl_xor(s1[r], 2);
            s1[r] += __shfl_xor(s1[r], 4);
            s1[r] += __shfl_xor(s1[r], 8);
            s2[r] += __shfl_xor(s2[r], 1);
            s2[r] += __shfl_xor(s2[r], 2);
            s2[r] += __shfl_xor(s2[r], 4);
            s2[r] += __shfl_xor(s2[r], 8);
        }
#pragma unroll
        for (int r = 0; r < 4; ++r) {
            float avg = s1[r] * (1.0f / (float)HH);
            float var = s2[r] * (1.0f / (float)HH) - avg * avg;
            float inv = rsqrtf(var + 1e-3f);
            float wv = 0.f;
#pragma unroll
            for (int nt = 0; nt < 3; ++nt) {
                float z = (h[nt][r] - avg) * inv;
                float ps = 1.0f / (1.0f + __expf(-z));
                float f = fmaf(ps, one_m_alv, alv);
                wv = fmaf(h[nt][r] * f, W2r[nt], wv);
            }
            wsum[r] = wv;
            wsum[r] += __shfl_xor(wsum[r], 1);
            wsum[r] += __shfl_xor(wsum[r], 2);
            wsum[r] += __shfl_xor(wsum[r], 4);
            wsum[r] += __shfl_xor(wsum[r], 8);
        }
        if (col == 0) {                      // pad rows land in shW[88..95], unread
            float4 o = {wsum[0] + b2v, wsum[1] + b2v, wsum[2] + b2v, wsum[3] + b2v};
            *(float4*)&shW[mt * 16 + q * 4] = o;
        }
    }
    __syncthreads();
    {   // pooling: out[b][d] += sum_s w[s]*hist[rowLo+s][d]
        const int rowLo = half ? 112 : 0, nR = half ? 88 : 112;
        const float* hb = hist + ((size_t)b * SS + rowLo) * DD;
        float p = 0.f;
        for (int s = wave; s < nR; s += 4)
            p = fmaf(shW[s], hb[(size_t)s * DD + lane], p);
        shPool[wave][lane] = p;
    }
    __syncthreads();
    if (t < DD)
        atomicAdd(out + b * DD + t,
                  shPool[0][t] + shPool[1][t] + shPool[2][t] + shPool[3][t]);
}

// ---------------------------------------------------------------------------
// Pass 2 (fallback when ws can't hold hG): full GEMM recompute epilogue.
// ---------------------------------------------------------------------------
template <bool WB>
__global__ __launch_bounds__(256, 6) void k_pass2(const float* __restrict__ hist,
                                                  const float* __restrict__ cand,
                                                  const float* __restrict__ W1,
                                                  const float* __restrict__ b1,
                                                  const unsigned short* __restrict__ WbG,
                                                  const float* __restrict__ baseG,
                                                  const float* __restrict__ Acoef,
                                                  const float* __restrict__ Bcoef,
                                                  const float* __restrict__ alpha,
                                                  const float* __restrict__ W2,
                                                  const float* __restrict__ b2,
                                                  float* __restrict__ out) {
    __shared__ unsigned short shH[112 * LDH];
    __shared__ unsigned short shWbT[NP * LDH];
    __shared__ float shC[WB ? 1 : DD], shBase[NP];
    __shared__ float shBaseP[WB ? 1 : 4][NP];
    __shared__ float shW[112];
    __shared__ float shPool[4][DD];
    int bx = blockIdx.x, b = bx >> 1, half = bx & 1;
    int t = threadIdx.x, wave = t >> 6, lane = t & 63;
    int col = lane & 15, q = lane >> 4;

    prologue<WB>(b, half, t, hist, cand, W1, b1, WbG, baseG, shH, shWbT, shC,
                 shBase, shBaseP);

    bf16x8 bfr[3][2];
    load_bfrags(shWbT, lane, bfr);
    float baseAB[3], Ar[3], W2r[3];
#pragma unroll
    for (int nt = 0; nt < 3; ++nt) {
        int c = nt * 16 + col;
        Ar[nt] = Acoef[c];
        baseAB[nt] = fmaf(shBase[c], Ar[nt], Bcoef[c]);
        W2r[nt] = (c < HH) ? W2[c] : 0.f;
    }
    float alv = alpha[0], one_m_alv = 1.0f - alv, b2v = b2[0];

    const int NTl = half ? 6 : 7;
    for (int mt = wave; mt < NTl; mt += 4) {
        f32x4 d[3];
        gemm_tile(shH, bfr, mt, lane, d);
        float hp[3][4];
#pragma unroll
        for (int nt = 0; nt < 3; ++nt)
#pragma unroll
            for (int r = 0; r < 4; ++r)
                hp[nt][r] = fmaf(d[nt][r], Ar[nt], baseAB[nt]);
        float s1[4], s2[4], wsum[4];
#pragma unroll
        for (int r = 0; r < 4; ++r) {
            s1[r] = hp[0][r] + hp[1][r] + hp[2][r];
            s2[r] = hp[0][r] * hp[0][r] + hp[1][r] * hp[1][r] + hp[2][r] * hp[2][r];
            s1[r] += __shfl_xor(s1[r], 1);
            s1[r] += __shfl_xor(s1[r], 2);
            s1[r] += __shfl_xor(s1[r], 4);
            s1[r] += __shfl_xor(s1[r], 8);
            s2[r] += __shfl_xor(s2[r], 1);
            s2[r] += __shfl_xor(s2[r], 2);
            s2[r] += __shfl_xor(s2[r], 4);
            s2[r] += __shfl_xor(s2[r], 8);
        }
#pragma unroll
        for (int r = 0; r < 4; ++r) {
            float avg = s1[r] * (1.0f / (float)HH);
            float var = s2[r] * (1.0f / (float)HH) - avg * avg;
            float inv = rsqrtf(var + 1e-3f);
            float wv = 0.f;
#pragma unroll
            for (int nt = 0; nt < 3; ++nt) {
                float z = (hp[nt][r] - avg) * inv;
                float ps = 1.0f / (1.0f + __expf(-z));
                float f = fmaf(ps, one_m_alv, alv);
                wv = fmaf(hp[nt][r] * f, W2r[nt], wv);
            }
            wsum[r] = wv;
            wsum[r] += __shfl_xor(wsum[r], 1);
            wsum[r] += __shfl_xor(wsum[r], 2);
            wsum[r] += __shfl_xor(wsum[r], 4);
            wsum[r] += __shfl_xor(wsum[r], 8);
        }
        if (col == 0) {
            float4 o = {wsum[0] + b2v, wsum[1] + b2v, wsum[2] + b2v, wsum[3] + b2v};
            *(float4*)&shW[mt * 16 + q * 4] = o;
        }
    }
    __syncthreads();
    {
        const int nR = half ? 88 : 112;
        float p = 0.f;
        for (int s = wave; s < nR; s += 4)
            p = fmaf(shW[s], bf2f(shH[s * LDH + lane]), p);
        shPool[wave][lane] = p;
    }
    __syncthreads();
    if (t < DD)
        atomicAdd(out + b * DD + t,
                  shPool[0][t] + shPool[1][t] + shPool[2][t] + shPool[3][t]);
}

// ---------------------------------------------------------------------------
extern "C" void kernel_launch(void* const* d_in, const int* in_sizes, int n_in,
                              void* d_out, int out_size, void* d_ws, size_t ws_size,
                              hipStream_t stream) {
    const float* hist = (const float*)d_in[0];
    const float* cand = (const float*)d_in[1];
    const float* W1 = (const float*)d_in[2];
    const float* b1 = (const float*)d_in[3];
    const float* gamma = (const float*)d_in[4];
    const float* beta = (const float*)d_in[5];
    const float* alpha = (const float*)d_in[6];
    const float* W2 = (const float*)d_in[7];
    const float* b2 = (const float*)d_in[8];
    float* out = (float*)d_out;
    float* ws = (float*)d_ws;

    const size_t pstatF = (size_t)NPB * PSTRIDE;      // 655360 floats
    const size_t baseF = (size_t)BB * NP;             // 196608 floats
    const size_t wbS = (size_t)BB * NP * DD;          // 9.4M shorts
    const size_t hS = (size_t)NPB * 7 * HSLOT;        // 44M shorts (88 MB)
    const size_t hdrF = pstatF + 2 * NP + baseF;      // pstat|A|Bc|baseG
    const size_t hstoreNeed = hdrF * 4 + (wbS + hS) * 2;   // ~110.4 MB
    const size_t fullNeed = hdrF * 4 + wbS * 2;            // ~22.3 MB
    const size_t midNeed = (pstatF + 2 * NP) * 4;          // ~2.63 MB

    hipMemsetAsync(out, 0, (size_t)out_size * sizeof(float), stream);
    if (ws_size >= hstoreNeed) {
        float* pstat = ws;
        float* A = pstat + pstatF;
        float* Bc = A + NP;
        float* baseG = Bc + NP;
        unsigned short* WbG = (unsigned short*)(baseG + baseF);
        unsigned short* hG = WbG + wbS;
        k_wb<<<BB, 256, 0, stream>>>(cand, W1, b1, WbG, baseG);
        k_pass1<true, true, true><<<NPB, 256, 0, stream>>>(
            hist, cand, W1, b1, WbG, baseG, hG, pstat, nullptr, nullptr);
        k_stats_red<<<NP, 256, 0, stream>>>(pstat, gamma, beta, A, Bc);
        k_pass3<<<NPB, 256, 0, stream>>>(hG, hist, A, Bc, alpha, W2, b2, out);
    } else if (ws_size >= fullNeed) {
        float* pstat = ws;
        float* A = pstat + pstatF;
        float* Bc = A + NP;
        float* baseG = Bc + NP;
        unsigned short* WbG = (unsigned short*)(baseG + baseF);
        k_wb<<<BB, 256, 0, stream>>>(cand, W1, b1, WbG, baseG);
        k_pass1<true, true, false><<<NPB, 256, 0, stream>>>(
            hist, cand, W1, b1, WbG, baseG, nullptr, pstat, nullptr, nullptr);
        k_stats_red<<<NP, 256, 0, stream>>>(pstat, gamma, beta, A, Bc);
        k_pass2<true><<<NPB, 256, 0, stream>>>(hist, cand, W1, b1, WbG, baseG, A, Bc,
                                               alpha, W2, b2, out);
    } else if (ws_size >= midNeed) {
        float* pstat = ws;
        float* A = pstat + pstatF;
        float* Bc = A + NP;
        k_pass1<false, true, false><<<NPB, 256, 0, stream>>>(
            hist, cand, W1, b1, nullptr, nullptr, nullptr, pstat, nullptr, nullptr);
        k_stats_red<<<NP, 256, 0, stream>>>(pstat, gamma, beta, A, Bc);
        k_pass2<false><<<NPB, 256, 0, stream>>>(hist, cand, W1, b1, nullptr, nullptr,
                                                A, Bc, alpha, W2, b2, out);
    } else {
        float* gsum = ws;
        float* gsum2 = ws + NP;
        float* A = ws + 2 * NP;
        float* Bc = ws + 3 * NP;
        hipMemsetAsync(gsum, 0, 2 * NP * sizeof(float), stream);
        k_pass1<false, false, false><<<NPB, 256, 0, stream>>>(
            hist, cand, W1, b1, nullptr, nullptr, nullptr, nullptr, gsum, gsum2);
        k_stats<<<1, 64, 0, stream>>>(gsum, gsum2, gamma, beta, A, Bc);
        k_pass2<false><<<NPB, 256, 0, stream>>>(hist, cand, W1, b1, nullptr, nullptr,
                                                A, Bc, alpha, W2, b2, out);
    }
}